// Round 11
// baseline (103.219 us; speedup 1.0000x reference)
//
#include <hip/hip_runtime.h>

// Problem: B=4, C=256, C4=64, N=4096, f32 in/out.
//   Q = Wqk@x; V = Wv@x + b; E = Q^T Q / 8; A = softmax_rows(E); out = V @ A
// Fused: out[c,m] = sum_n (V[c,n]/Z[n]) * exp(E[n,m]),  Z[n] = sum_m exp(E[n,m])
// exp via v_exp_f32: Qt scaled by sqrt(log2e/8). z: no shift (2^12 folded into
// u_kernel). av: SHIFT2=12 keeps P normal-f16. P stays IN REGISTERS (E-MFMA
// D-layout == PV B-frag of mfma_f32_16x16x16f16).
// R11: av m-tile 32 / 8 waves / (512,4) -> working set ~120 regs fits the
// 128 cap, NO spill (R10: WRITE 53MB of scratch); 256/8=32 even strips, no
// ragged guard; phase-separated E->exp2->PV step for ILP.
// z: 4x m-work per wave (4 preloaded 128-m chunks) to amortize prologue/tail.

#define CC 256
#define C4C 64
#define NBATCH 4
#define NN 4096
#define QSCALE 0.42466089f   // sqrt(log2(e)/8)
#define SHIFT2 12.0f

typedef _Float16 f16;
typedef _Float16 half2v __attribute__((ext_vector_type(2)));
typedef _Float16 half4 __attribute__((ext_vector_type(4)));
typedef _Float16 half8 __attribute__((ext_vector_type(8)));
typedef __fp16 fp16x2 __attribute__((ext_vector_type(2)));
typedef float floatx4 __attribute__((ext_vector_type(4)));

static __device__ __forceinline__ half2v pkrtz(float a, float b) {
  fp16x2 r = __builtin_amdgcn_cvt_pkrtz(a, b);
  return __builtin_bit_cast(half2v, r);
}

// ---------------- QV: Q/V projections via MFMA ----------------
// grid (128, 4) block 256 (4 waves). Block tile: 128 oc x 32 n, K=C=256.
#define XT_PITCH 264
__global__ __launch_bounds__(256) void qv_kernel(
    const float* __restrict__ x, const float* __restrict__ Wqk,
    const float* __restrict__ Wv, const float* __restrict__ bv,
    f16* __restrict__ Qt, float* __restrict__ V)
{
  __shared__ __align__(16) f16 xt[32][XT_PITCH];
  const int b = blockIdx.y;
  const int n0 = blockIdx.x * 32;
  const int tid = threadIdx.x;

  {
    const int nq = tid & 7;
    const int cb = tid >> 3;
    const int c = cb * 8;
    const float* xp = x + (size_t)b * CC * NN + n0 + nq * 4;
    float4 r[8];
#pragma unroll
    for (int j = 0; j < 8; ++j)
      r[j] = *(const float4*)(xp + (size_t)(c + j) * NN);
#pragma unroll
    for (int s = 0; s < 4; ++s) {
      half8 h;
#pragma unroll
      for (int j = 0; j < 8; ++j) h[j] = (f16)(((const float*)&r[j])[s]);
      *(half8*)(&xt[nq * 4 + s][c]) = h;
    }
  }

  const int w = tid >> 6, l = tid & 63, lr = l & 15, lg = l >> 4;
  const float* Wsrc = (w < 2) ? Wqk : Wv;
  const int ocb = (w & 1) * 32;
  half8 af[2][8];
#pragma unroll
  for (int t = 0; t < 2; ++t) {
    const float* wp = Wsrc + (size_t)(ocb + t * 16 + lr) * CC + 8 * lg;
#pragma unroll
    for (int kk = 0; kk < 8; ++kk) {
      float4 wa = *(const float4*)(wp + kk * 32);
      float4 wb = *(const float4*)(wp + kk * 32 + 4);
      half8 h;
      h[0] = (f16)wa.x; h[1] = (f16)wa.y; h[2] = (f16)wa.z; h[3] = (f16)wa.w;
      h[4] = (f16)wb.x; h[5] = (f16)wb.y; h[6] = (f16)wb.z; h[7] = (f16)wb.w;
      af[t][kk] = h;
    }
  }

  __syncthreads();

  floatx4 acc[2][2] = {{{0.f,0.f,0.f,0.f},{0.f,0.f,0.f,0.f}},
                       {{0.f,0.f,0.f,0.f},{0.f,0.f,0.f,0.f}}};
#pragma unroll
  for (int nt = 0; nt < 2; ++nt) {
#pragma unroll
    for (int kk = 0; kk < 8; ++kk) {
      half8 bf = *(const half8*)(&xt[nt * 16 + lr][kk * 32 + 8 * lg]);
      acc[0][nt] = __builtin_amdgcn_mfma_f32_16x16x32_f16(af[0][kk], bf, acc[0][nt], 0, 0, 0);
      acc[1][nt] = __builtin_amdgcn_mfma_f32_16x16x32_f16(af[1][kk], bf, acc[1][nt], 0, 0, 0);
    }
  }

  if (w < 2) {
#pragma unroll
    for (int t = 0; t < 2; ++t)
#pragma unroll
      for (int nt = 0; nt < 2; ++nt) {
        int n = n0 + nt * 16 + lr;
        int oc = w * 32 + t * 16 + 4 * lg;
        union { f16 h[4]; unsigned long long u; } q4;
#pragma unroll
        for (int i = 0; i < 4; ++i) q4.h[i] = (f16)(acc[t][nt][i] * QSCALE);
        *(unsigned long long*)(Qt + ((size_t)(b * NN) + n) * 64 + oc) = q4.u;
      }
  } else {
#pragma unroll
    for (int t = 0; t < 2; ++t)
#pragma unroll
      for (int nt = 0; nt < 2; ++nt) {
        int n = n0 + nt * 16 + lr;
        int oc = (w - 2) * 32 + t * 16 + 4 * lg;
#pragma unroll
        for (int i = 0; i < 4; ++i)
          V[((size_t)(b * C4C) + oc + i) * NN + n] = acc[t][nt][i] + bv[oc + i];
      }
  }
}

// ---------------- Z pass: 4x m-work per wave, full-chunk preload -------------
// Zp[mh][b][n0..n0+32) partial over a 2048-m half. grid 1024 (XCD-swizzled),
// block 256 (4 waves). Wave w: 512 m = 4 chunks of 128 (8 B-frag pairs each).
__global__ __launch_bounds__(256) void z_kernel(
    const f16* __restrict__ Qt, float* __restrict__ Zp)
{
  __shared__ float zl[4][32];
  const int bx = blockIdx.x;
  const int xcd = bx & 7, slot = bx >> 3;       // slot 0..127
  const int b = xcd >> 1;                        // 2 XCDs per batch
  const int wu = ((xcd & 1) << 7) | slot;        // 0..255 per batch
  const int n0 = (wu >> 1) * 32;                 // nb 0..127
  const int mh = wu & 1;                         // m half
  const int tid = threadIdx.x;
  const int w = tid >> 6, l = tid & 63, lr = l & 15, lg = l >> 4;
  const f16* Qb = Qt + (size_t)b * NN * 64;

  half8 a[2][2];
#pragma unroll
  for (int t = 0; t < 2; ++t) {
    const f16* ap = Qb + ((size_t)(n0 + 16 * t + lr)) * 64 + 8 * lg;
    a[t][0] = *(const half8*)(ap);
    a[t][1] = *(const half8*)(ap + 32);
  }

  float rs[2][4] = {{0.f,0.f,0.f,0.f},{0.f,0.f,0.f,0.f}};
#pragma unroll 1
  for (int mch = 0; mch < 4; ++mch) {
    const int mbeg = mh * 2048 + w * 512 + mch * 128;
    half8 bb[8][2];
#pragma unroll
    for (int mt = 0; mt < 8; ++mt) {
      const f16* bp = Qb + ((size_t)(mbeg + mt * 16 + lr)) * 64 + 8 * lg;
      bb[mt][0] = *(const half8*)(bp);
      bb[mt][1] = *(const half8*)(bp + 32);
    }
#pragma unroll
    for (int mt = 0; mt < 8; ++mt) {
#pragma unroll
      for (int t = 0; t < 2; ++t) {
        floatx4 d = {0.f, 0.f, 0.f, 0.f};
        d = __builtin_amdgcn_mfma_f32_16x16x32_f16(a[t][0], bb[mt][0], d, 0, 0, 0);
        d = __builtin_amdgcn_mfma_f32_16x16x32_f16(a[t][1], bb[mt][1], d, 0, 0, 0);
#pragma unroll
        for (int i = 0; i < 4; ++i) rs[t][i] += __builtin_amdgcn_exp2f(d[i]);
      }
    }
  }
#pragma unroll
  for (int t = 0; t < 2; ++t)
#pragma unroll
    for (int i = 0; i < 4; ++i) {
      float v = rs[t][i];
      v += __shfl_xor(v, 1); v += __shfl_xor(v, 2);
      v += __shfl_xor(v, 4); v += __shfl_xor(v, 8);
      rs[t][i] = v;
    }
  if (lr == 0) {
#pragma unroll
    for (int t = 0; t < 2; ++t)
#pragma unroll
      for (int i = 0; i < 4; ++i)
        zl[w][16 * t + 4 * lg + i] = rs[t][i];
  }
  __syncthreads();
  if (tid < 32) {   // fixed-order cross-wave sum: deterministic
    float s = zl[0][tid] + zl[1][tid] + zl[2][tid] + zl[3][tid];
    Zp[(size_t)mh * NBATCH * NN + b * NN + n0 + tid] = s;
  }
}

// ---------------- Z reduce: Z[i] = Zp[0][i] + Zp[1][i] (fixed order) ----------
__global__ __launch_bounds__(256) void zr_kernel(
    const float* __restrict__ Zp, float* __restrict__ Z)
{
  int i = blockIdx.x * 256 + threadIdx.x;   // 4*4096 = 16384
  Z[i] = Zp[i] + Zp[(size_t)NBATCH * NN + i];
}

// ---------------- U: blocked U4[b][n/16][c][16] = V * 2^12 / Zraw (fp16) -------
__global__ __launch_bounds__(256) void u_kernel(
    const float* __restrict__ V, const float* __restrict__ Z,
    f16* __restrict__ U4)
{
  size_t t = (size_t)blockIdx.x * 256 + threadIdx.x;  // 128K threads
  size_t e = t * 8;
  int b = (int)(e >> 18);
  int c = (int)((e >> 12) & 63);
  int n = (int)(e & (NN - 1));
  const float* vp = V + (size_t)b * C4C * NN + (size_t)c * NN + n;
  float4 v0 = *(const float4*)(vp);
  float4 v1 = *(const float4*)(vp + 4);
  const float* zp = Z + b * NN + n;
  float4 z0 = *(const float4*)(zp);
  float4 z1 = *(const float4*)(zp + 4);
  half2v h0 = pkrtz(v0.x * 4096.0f / z0.x, v0.y * 4096.0f / z0.y);
  half2v h1 = pkrtz(v0.z * 4096.0f / z0.z, v0.w * 4096.0f / z0.w);
  half2v h2 = pkrtz(v1.x * 4096.0f / z1.x, v1.y * 4096.0f / z1.y);
  half2v h3 = pkrtz(v1.z * 4096.0f / z1.z, v1.w * 4096.0f / z1.w);
  half8 h = {h0[0], h0[1], h1[0], h1[1], h2[0], h2[1], h3[0], h3[1]};
  *(half8*)(U4 + (size_t)b * (C4C * NN) + (size_t)(n >> 4) * 1024 + c * 16 + (n & 15)) = h;
}

// ---------------- PV pass: m32, 8 waves, phase-separated, no spill -----------
// grid 512 (1D, XCD-swizzled) block 512 (8 waves, (512,4): 128-reg cap).
// Block: 32 m-cols, all 4096 n (256 strips). Wave w: strips w, w+8, ... (32 even).
// Step: E-MFMA x4 (d0,d1 chains) -> exp2 x8 -> pkrtz -> PV-MFMA x8 (K=16).
// Rotating even/odd prefetch of (A-frags, ua).
// End: fixed-order 8-wave LDS reduction (deterministic), direct stores.
#define LOADA(NS, A0, A1)                                                  \
  { const f16* ap_ = Qb + ((size_t)((NS) + lr)) * 64 + 8 * lg;             \
    A0 = *(const half8*)(ap_); A1 = *(const half8*)(ap_ + 32); }

#define LOADU(NB, UA)                                                      \
  { const f16* up_ = Ub + (size_t)(NB) * 1024 + 4 * lg;                    \
    _Pragma("unroll")                                                      \
    for (int cs = 0; cs < 4; ++cs)                                         \
      UA[cs] = *(const half4*)(up_ + (16 * cs + lr) * 16); }

#define AV_STEP32(A0, A1, UA)                                              \
  { floatx4 d0 = {0.f,0.f,0.f,0.f}, d1 = {0.f,0.f,0.f,0.f};                \
    d0 = __builtin_amdgcn_mfma_f32_16x16x32_f16(A0, bq[0][0], d0, 0, 0, 0);\
    d1 = __builtin_amdgcn_mfma_f32_16x16x32_f16(A0, bq[1][0], d1, 0, 0, 0);\
    d0 = __builtin_amdgcn_mfma_f32_16x16x32_f16(A1, bq[0][1], d0, 0, 0, 0);\
    d1 = __builtin_amdgcn_mfma_f32_16x16x32_f16(A1, bq[1][1], d1, 0, 0, 0);\
    half2v p0a = pkrtz(__builtin_amdgcn_exp2f(d0[0] - SHIFT2),             \
                       __builtin_amdgcn_exp2f(d0[1] - SHIFT2));            \
    half2v p0b = pkrtz(__builtin_amdgcn_exp2f(d0[2] - SHIFT2),             \
                       __builtin_amdgcn_exp2f(d0[3] - SHIFT2));            \
    half2v p1a = pkrtz(__builtin_amdgcn_exp2f(d1[0] - SHIFT2),             \
                       __builtin_amdgcn_exp2f(d1[1] - SHIFT2));            \
    half2v p1b = pkrtz(__builtin_amdgcn_exp2f(d1[2] - SHIFT2),             \
                       __builtin_amdgcn_exp2f(d1[3] - SHIFT2));            \
    half4 bt0 = {p0a[0], p0a[1], p0b[0], p0b[1]};                          \
    half4 bt1 = {p1a[0], p1a[1], p1b[0], p1b[1]};                          \
    _Pragma("unroll")                                                      \
    for (int cs = 0; cs < 4; ++cs) {                                       \
      o[cs][0] = __builtin_amdgcn_mfma_f32_16x16x16f16(UA[cs], bt0, o[cs][0], 0, 0, 0); \
      o[cs][1] = __builtin_amdgcn_mfma_f32_16x16x16f16(UA[cs], bt1, o[cs][1], 0, 0, 0); } }

__global__ __launch_bounds__(512, 4) void av_kernel(
    const f16* __restrict__ Qt, const f16* __restrict__ U4,
    float* __restrict__ Out)
{
  __shared__ float red[8][2][16][17];  // ~17.4 KB

  const int bx = blockIdx.x;
  const int xcd = bx & 7, slot = bx >> 3;          // slot 0..63
  const int b = xcd >> 1;                          // 2 XCDs per batch
  const int m0 = (((xcd & 1) << 6) | slot) * 32;   // 128 m-tiles per batch
  const int tid = threadIdx.x;
  const int w = tid >> 6;                          // 0..7
  const int l = tid & 63;
  const int lr = l & 15, lg = l >> 4;

  const f16* Qb = Qt + (size_t)b * NN * 64;
  const f16* Ub = U4 + (size_t)b * (C4C * NN);

  // hoisted E B-frags for the 32-m tile
  half8 bq[2][2];
#pragma unroll
  for (int t = 0; t < 2; ++t) {
    const f16* bp = Qb + ((size_t)(m0 + 16 * t + lr)) * 64 + 8 * lg;
    bq[t][0] = *(const half8*)(bp);
    bq[t][1] = *(const half8*)(bp + 32);
  }

  floatx4 o[4][2];
#pragma unroll
  for (int cs = 0; cs < 4; ++cs)
#pragma unroll
    for (int t = 0; t < 2; ++t) o[cs][t] = (floatx4){0.f, 0.f, 0.f, 0.f};

  // 32 even steps: strips s = w, w+8, ..., w+248. Rotating prefetch.
  int s = w;
  half8 aA0, aA1, aB0, aB1;
  half4 uA[4], uB[4];
  LOADA(s * 16, aA0, aA1);
  LOADU(s, uA);
#pragma unroll 1
  for (int k = 0; k < 32; k += 2) {
    int s1 = s + 8;  s1 = (s1 < 256) ? s1 : 0;
    LOADA(s1 * 16, aB0, aB1);
    LOADU(s1, uB);
    AV_STEP32(aA0, aA1, uA);
    int s2 = s + 16; s2 = (s2 < 256) ? s2 : 0;
    LOADA(s2 * 16, aA0, aA1);
    LOADU(s2, uA);
    AV_STEP32(aB0, aB1, uB);
    s = s + 16;
  }

  // ---- 8-wave reduction, fixed order: deterministic, no atomics ----
#pragma unroll 1
  for (int cs = 0; cs < 4; ++cs) {
    __syncthreads();
#pragma unroll
    for (int t = 0; t < 2; ++t)
#pragma unroll
      for (int i = 0; i < 4; ++i)
        red[w][t][4 * lg + i][lr] = o[cs][t][i];
    __syncthreads();
    const int t = tid >> 8;              // 0..1
    const int r = (tid >> 4) & 15;       // 0..15
    const int col = tid & 15;            // 0..15
    float ssum = 0.f;
#pragma unroll
    for (int ww = 0; ww < 8; ++ww) ssum += red[ww][t][r][col];
    Out[((size_t)b * C4C + cs * 16 + r) * NN + m0 + t * 16 + col] = ssum;
  }
}

// ---------------- launch ----------------
// ws layout (~8.45 MB, Zp aliased over U4 region — dead before U4 is written):
//   Qt  f16 [4][4096][64]      2 MiB    @ 0
//   V   f32 [4][64][4096]      4 MiB    @ 2 MiB
//   Z   f32 [4][4096]          64 KiB   @ 6 MiB
//   U4  f16 [4][256][64][16]   2 MiB    @ 6 MiB + 64 KiB
//   Zp  f32 [2][4][4096]       128 KiB  @ 6 MiB + 64 KiB (aliases U4)
extern "C" void kernel_launch(void* const* d_in, const int* in_sizes, int n_in,
                              void* d_out, int out_size, void* d_ws, size_t ws_size,
                              hipStream_t stream)
{
  const float* x   = (const float*)d_in[0];
  const float* Wqk = (const float*)d_in[1];
  const float* Wv  = (const float*)d_in[2];
  const float* bv  = (const float*)d_in[3];
  float* out = (float*)d_out;

  char* ws = (char*)d_ws;
  f16*   Qt = (f16*)(ws);
  float* V  = (float*)(ws + (2u << 20));
  float* Z  = (float*)(ws + (6u << 20));
  f16*   U4 = (f16*)(ws + (6u << 20) + (64u << 10));
  float* Zp = (float*)(ws + (6u << 20) + (64u << 10));  // alias: dead before U4

  qv_kernel<<<dim3(128, 4), 256, 0, stream>>>(x, Wqk, Wv, bv, Qt, V);
  z_kernel<<<dim3(1024), 256, 0, stream>>>(Qt, Zp);
  zr_kernel<<<dim3(64), 256, 0, stream>>>(Zp, Z);
  u_kernel<<<dim3(512), 256, 0, stream>>>(V, Z, U4);
  av_kernel<<<dim3(512), 512, 0, stream>>>(Qt, U4, out);
}

// Round 12
// 102.722 us; speedup vs baseline: 1.0048x; 1.0048x over previous
//
#include <hip/hip_runtime.h>

// Problem: B=4, C=256, C4=64, N=4096, f32 in/out.
//   Q = Wqk@x; V = Wv@x + b; E = Q^T Q / 8; A = softmax_rows(E); out = V @ A
// Fused: out[c,m] = sum_n (V[c,n]/Z[n]) * exp(E[n,m]),  Z[n] = sum_m exp(E[n,m])
// exp via v_exp_f32: Qt scaled by sqrt(log2e/8). z: no shift (2^12 folded into
// u_kernel). av: SHIFT2=12 keeps P normal-f16. P stays IN REGISTERS (E-MFMA
// D-layout == PV B-frag of mfma_f32_16x16x16f16).
// R12: 2-STAGE SOFTWARE PIPELINE in both z and av — iteration i issues
// E-MFMA(i) while running exp2/pkrtz/PV on step i-1's D regs (breaks the
// per-step serial chain E->exp2->PV that six stuck variants shared).
// All pipeline buffers depth-2, named regs, unroll-2 (no runtime indexing).

#define CC 256
#define C4C 64
#define NBATCH 4
#define NN 4096
#define QSCALE 0.42466089f   // sqrt(log2(e)/8)
#define SHIFT2 12.0f

typedef _Float16 f16;
typedef _Float16 half2v __attribute__((ext_vector_type(2)));
typedef _Float16 half4 __attribute__((ext_vector_type(4)));
typedef _Float16 half8 __attribute__((ext_vector_type(8)));
typedef __fp16 fp16x2 __attribute__((ext_vector_type(2)));
typedef float floatx4 __attribute__((ext_vector_type(4)));

static __device__ __forceinline__ half2v pkrtz(float a, float b) {
  fp16x2 r = __builtin_amdgcn_cvt_pkrtz(a, b);
  return __builtin_bit_cast(half2v, r);
}

// ---------------- QV: Q/V projections via MFMA ----------------
// grid (128, 4) block 256 (4 waves). Block tile: 128 oc x 32 n, K=C=256.
#define XT_PITCH 264
__global__ __launch_bounds__(256) void qv_kernel(
    const float* __restrict__ x, const float* __restrict__ Wqk,
    const float* __restrict__ Wv, const float* __restrict__ bv,
    f16* __restrict__ Qt, float* __restrict__ V)
{
  __shared__ __align__(16) f16 xt[32][XT_PITCH];
  const int b = blockIdx.y;
  const int n0 = blockIdx.x * 32;
  const int tid = threadIdx.x;

  {
    const int nq = tid & 7;
    const int cb = tid >> 3;
    const int c = cb * 8;
    const float* xp = x + (size_t)b * CC * NN + n0 + nq * 4;
    float4 r[8];
#pragma unroll
    for (int j = 0; j < 8; ++j)
      r[j] = *(const float4*)(xp + (size_t)(c + j) * NN);
#pragma unroll
    for (int s = 0; s < 4; ++s) {
      half8 h;
#pragma unroll
      for (int j = 0; j < 8; ++j) h[j] = (f16)(((const float*)&r[j])[s]);
      *(half8*)(&xt[nq * 4 + s][c]) = h;
    }
  }

  const int w = tid >> 6, l = tid & 63, lr = l & 15, lg = l >> 4;
  const float* Wsrc = (w < 2) ? Wqk : Wv;
  const int ocb = (w & 1) * 32;
  half8 af[2][8];
#pragma unroll
  for (int t = 0; t < 2; ++t) {
    const float* wp = Wsrc + (size_t)(ocb + t * 16 + lr) * CC + 8 * lg;
#pragma unroll
    for (int kk = 0; kk < 8; ++kk) {
      float4 wa = *(const float4*)(wp + kk * 32);
      float4 wb = *(const float4*)(wp + kk * 32 + 4);
      half8 h;
      h[0] = (f16)wa.x; h[1] = (f16)wa.y; h[2] = (f16)wa.z; h[3] = (f16)wa.w;
      h[4] = (f16)wb.x; h[5] = (f16)wb.y; h[6] = (f16)wb.z; h[7] = (f16)wb.w;
      af[t][kk] = h;
    }
  }

  __syncthreads();

  floatx4 acc[2][2] = {{{0.f,0.f,0.f,0.f},{0.f,0.f,0.f,0.f}},
                       {{0.f,0.f,0.f,0.f},{0.f,0.f,0.f,0.f}}};
#pragma unroll
  for (int nt = 0; nt < 2; ++nt) {
#pragma unroll
    for (int kk = 0; kk < 8; ++kk) {
      half8 bf = *(const half8*)(&xt[nt * 16 + lr][kk * 32 + 8 * lg]);
      acc[0][nt] = __builtin_amdgcn_mfma_f32_16x16x32_f16(af[0][kk], bf, acc[0][nt], 0, 0, 0);
      acc[1][nt] = __builtin_amdgcn_mfma_f32_16x16x32_f16(af[1][kk], bf, acc[1][nt], 0, 0, 0);
    }
  }

  if (w < 2) {
#pragma unroll
    for (int t = 0; t < 2; ++t)
#pragma unroll
      for (int nt = 0; nt < 2; ++nt) {
        int n = n0 + nt * 16 + lr;
        int oc = w * 32 + t * 16 + 4 * lg;
        union { f16 h[4]; unsigned long long u; } q4;
#pragma unroll
        for (int i = 0; i < 4; ++i) q4.h[i] = (f16)(acc[t][nt][i] * QSCALE);
        *(unsigned long long*)(Qt + ((size_t)(b * NN) + n) * 64 + oc) = q4.u;
      }
  } else {
#pragma unroll
    for (int t = 0; t < 2; ++t)
#pragma unroll
      for (int nt = 0; nt < 2; ++nt) {
        int n = n0 + nt * 16 + lr;
        int oc = (w - 2) * 32 + t * 16 + 4 * lg;
#pragma unroll
        for (int i = 0; i < 4; ++i)
          V[((size_t)(b * C4C) + oc + i) * NN + n] = acc[t][nt][i] + bv[oc + i];
      }
  }
}

// ---------------- Z pass: 2-stage pipeline (E(t) || SM(t-1)) -----------------
// Zp[mh][b][n0..n0+32) partial over a 2048-m half. grid 1024 (XCD-swizzled),
// block 256 (4 waves). Wave w: 512 m = 4 chunks of 128 (preloaded, 8 tiles).
#define Z_PRELOAD(MBEG)                                                    \
  { _Pragma("unroll")                                                      \
    for (int mt = 0; mt < 8; ++mt) {                                       \
      const f16* bp_ = Qb + ((size_t)((MBEG) + mt * 16 + lr)) * 64 + 8 * lg; \
      bb[mt][0] = *(const half8*)(bp_);                                    \
      bb[mt][1] = *(const half8*)(bp_ + 32);                               \
    } }

#define Z_E(MT, D0, D1)                                                    \
  { D0 = (floatx4){0.f,0.f,0.f,0.f}; D1 = (floatx4){0.f,0.f,0.f,0.f};      \
    D0 = __builtin_amdgcn_mfma_f32_16x16x32_f16(a[0][0], bb[MT][0], D0, 0, 0, 0); \
    D1 = __builtin_amdgcn_mfma_f32_16x16x32_f16(a[1][0], bb[MT][0], D1, 0, 0, 0); \
    D0 = __builtin_amdgcn_mfma_f32_16x16x32_f16(a[0][1], bb[MT][1], D0, 0, 0, 0); \
    D1 = __builtin_amdgcn_mfma_f32_16x16x32_f16(a[1][1], bb[MT][1], D1, 0, 0, 0); }

#define Z_SM(D0, D1)                                                       \
  { _Pragma("unroll")                                                      \
    for (int i = 0; i < 4; ++i) {                                          \
      rs[0][i] += __builtin_amdgcn_exp2f(D0[i]);                           \
      rs[1][i] += __builtin_amdgcn_exp2f(D1[i]); } }

#define Z_TILES17                                                          \
  Z_E(1, dB0, dB1); Z_SM(dA0, dA1);                                        \
  Z_E(2, dA0, dA1); Z_SM(dB0, dB1);                                        \
  Z_E(3, dB0, dB1); Z_SM(dA0, dA1);                                        \
  Z_E(4, dA0, dA1); Z_SM(dB0, dB1);                                        \
  Z_E(5, dB0, dB1); Z_SM(dA0, dA1);                                        \
  Z_E(6, dA0, dA1); Z_SM(dB0, dB1);                                        \
  Z_E(7, dB0, dB1); Z_SM(dA0, dA1);

__global__ __launch_bounds__(256) void z_kernel(
    const f16* __restrict__ Qt, float* __restrict__ Zp)
{
  __shared__ float zl[4][32];
  const int bx = blockIdx.x;
  const int xcd = bx & 7, slot = bx >> 3;       // slot 0..127
  const int b = xcd >> 1;                        // 2 XCDs per batch
  const int wu = ((xcd & 1) << 7) | slot;        // 0..255 per batch
  const int n0 = (wu >> 1) * 32;                 // nb 0..127
  const int mh = wu & 1;                         // m half
  const int tid = threadIdx.x;
  const int w = tid >> 6, l = tid & 63, lr = l & 15, lg = l >> 4;
  const f16* Qb = Qt + (size_t)b * NN * 64;

  half8 a[2][2];
#pragma unroll
  for (int t = 0; t < 2; ++t) {
    const f16* ap = Qb + ((size_t)(n0 + 16 * t + lr)) * 64 + 8 * lg;
    a[t][0] = *(const half8*)(ap);
    a[t][1] = *(const half8*)(ap + 32);
  }

  const int mstr = mh * 2048 + w * 512;
  half8 bb[8][2];
  floatx4 dA0, dA1, dB0, dB1;
  float rs[2][4] = {{0.f,0.f,0.f,0.f},{0.f,0.f,0.f,0.f}};

  // chunk 0: tiles 0..7 (tile 7 left pending in dB)
  Z_PRELOAD(mstr);
  Z_E(0, dA0, dA1);
  Z_TILES17;
  // chunks 1..3: SM(pending) covers preload latency, then same pattern
#pragma unroll 1
  for (int mch = 1; mch < 4; ++mch) {
    Z_PRELOAD(mstr + mch * 128);
    Z_SM(dB0, dB1);          // tile 8*mch - 1
    Z_E(0, dA0, dA1);        // tile 8*mch
    Z_TILES17;
  }
  Z_SM(dB0, dB1);            // drain tile 31

#pragma unroll
  for (int t = 0; t < 2; ++t)
#pragma unroll
    for (int i = 0; i < 4; ++i) {
      float v = rs[t][i];
      v += __shfl_xor(v, 1); v += __shfl_xor(v, 2);
      v += __shfl_xor(v, 4); v += __shfl_xor(v, 8);
      rs[t][i] = v;
    }
  if (lr == 0) {
#pragma unroll
    for (int t = 0; t < 2; ++t)
#pragma unroll
      for (int i = 0; i < 4; ++i)
        zl[w][16 * t + 4 * lg + i] = rs[t][i];
  }
  __syncthreads();
  if (tid < 32) {   // fixed-order cross-wave sum: deterministic
    float s = zl[0][tid] + zl[1][tid] + zl[2][tid] + zl[3][tid];
    Zp[(size_t)mh * NBATCH * NN + b * NN + n0 + tid] = s;
  }
}

// ---------------- Z reduce: Z[i] = Zp[0][i] + Zp[1][i] (fixed order) ----------
__global__ __launch_bounds__(256) void zr_kernel(
    const float* __restrict__ Zp, float* __restrict__ Z)
{
  int i = blockIdx.x * 256 + threadIdx.x;   // 4*4096 = 16384
  Z[i] = Zp[i] + Zp[(size_t)NBATCH * NN + i];
}

// ---------------- U: blocked U4[b][n/16][c][16] = V * 2^12 / Zraw (fp16) -------
__global__ __launch_bounds__(256) void u_kernel(
    const float* __restrict__ V, const float* __restrict__ Z,
    f16* __restrict__ U4)
{
  size_t t = (size_t)blockIdx.x * 256 + threadIdx.x;  // 128K threads
  size_t e = t * 8;
  int b = (int)(e >> 18);
  int c = (int)((e >> 12) & 63);
  int n = (int)(e & (NN - 1));
  const float* vp = V + (size_t)b * C4C * NN + (size_t)c * NN + n;
  float4 v0 = *(const float4*)(vp);
  float4 v1 = *(const float4*)(vp + 4);
  const float* zp = Z + b * NN + n;
  float4 z0 = *(const float4*)(zp);
  float4 z1 = *(const float4*)(zp + 4);
  half2v h0 = pkrtz(v0.x * 4096.0f / z0.x, v0.y * 4096.0f / z0.y);
  half2v h1 = pkrtz(v0.z * 4096.0f / z0.z, v0.w * 4096.0f / z0.w);
  half2v h2 = pkrtz(v1.x * 4096.0f / z1.x, v1.y * 4096.0f / z1.y);
  half2v h3 = pkrtz(v1.z * 4096.0f / z1.z, v1.w * 4096.0f / z1.w);
  half8 h = {h0[0], h0[1], h1[0], h1[1], h2[0], h2[1], h3[0], h3[1]};
  *(half8*)(U4 + (size_t)b * (C4C * NN) + (size_t)(n >> 4) * 1024 + c * 16 + (n & 15)) = h;
}

// ---------------- PV pass: 2-stage pipeline (E(i) || SMPV(i-1)) --------------
// grid 512 (1D, XCD-swizzled) block 512 (8 waves, (512,4): 128-reg cap).
// Block: 32 m-cols, all 4096 n (256 strips). Wave w: strips w, w+8*i (32 steps).
// Iter i: SMPV(i-1) [exp2+pkrtz+PV on drained D] -> LOAD(i+1) -> E-MFMA(i).
// All pipeline buffers depth-2, named regs. ~116 VGPR, no spill.
// End: fixed-order 8-wave LDS reduction (deterministic), direct stores.
#define LOADA(NS, A0, A1)                                                  \
  { const f16* ap_ = Qb + ((size_t)((NS) + lr)) * 64 + 8 * lg;             \
    A0 = *(const half8*)(ap_); A1 = *(const half8*)(ap_ + 32); }

#define LOADU(NB, UA)                                                      \
  { const f16* up_ = Ub + (size_t)(NB) * 1024 + 4 * lg;                    \
    _Pragma("unroll")                                                      \
    for (int cs = 0; cs < 4; ++cs)                                         \
      UA[cs] = *(const half4*)(up_ + (16 * cs + lr) * 16); }

#define E_STEP(A0, A1, DA, DB)                                             \
  { DA = (floatx4){0.f,0.f,0.f,0.f}; DB = (floatx4){0.f,0.f,0.f,0.f};      \
    DA = __builtin_amdgcn_mfma_f32_16x16x32_f16(A0, bq[0][0], DA, 0, 0, 0);\
    DB = __builtin_amdgcn_mfma_f32_16x16x32_f16(A0, bq[1][0], DB, 0, 0, 0);\
    DA = __builtin_amdgcn_mfma_f32_16x16x32_f16(A1, bq[0][1], DA, 0, 0, 0);\
    DB = __builtin_amdgcn_mfma_f32_16x16x32_f16(A1, bq[1][1], DB, 0, 0, 0); }

#define SMPV(DA, DB, UA)                                                   \
  { half2v p0a = pkrtz(__builtin_amdgcn_exp2f(DA[0] - SHIFT2),             \
                       __builtin_amdgcn_exp2f(DA[1] - SHIFT2));            \
    half2v p0b = pkrtz(__builtin_amdgcn_exp2f(DA[2] - SHIFT2),             \
                       __builtin_amdgcn_exp2f(DA[3] - SHIFT2));            \
    half2v p1a = pkrtz(__builtin_amdgcn_exp2f(DB[0] - SHIFT2),             \
                       __builtin_amdgcn_exp2f(DB[1] - SHIFT2));            \
    half2v p1b = pkrtz(__builtin_amdgcn_exp2f(DB[2] - SHIFT2),             \
                       __builtin_amdgcn_exp2f(DB[3] - SHIFT2));            \
    half4 bt0 = {p0a[0], p0a[1], p0b[0], p0b[1]};                          \
    half4 bt1 = {p1a[0], p1a[1], p1b[0], p1b[1]};                          \
    _Pragma("unroll")                                                      \
    for (int cs = 0; cs < 4; ++cs) {                                       \
      o[cs][0] = __builtin_amdgcn_mfma_f32_16x16x16f16(UA[cs], bt0, o[cs][0], 0, 0, 0); \
      o[cs][1] = __builtin_amdgcn_mfma_f32_16x16x16f16(UA[cs], bt1, o[cs][1], 0, 0, 0); } }

__global__ __launch_bounds__(512, 4) void av_kernel(
    const f16* __restrict__ Qt, const f16* __restrict__ U4,
    float* __restrict__ Out)
{
  __shared__ float red[8][2][16][17];  // ~17.4 KB

  const int bx = blockIdx.x;
  const int xcd = bx & 7, slot = bx >> 3;          // slot 0..63
  const int b = xcd >> 1;                          // 2 XCDs per batch
  const int m0 = (((xcd & 1) << 6) | slot) * 32;   // 128 m-tiles per batch
  const int tid = threadIdx.x;
  const int w = tid >> 6;                          // 0..7
  const int l = tid & 63;
  const int lr = l & 15, lg = l >> 4;

  const f16* Qb = Qt + (size_t)b * NN * 64;
  const f16* Ub = U4 + (size_t)b * (C4C * NN);

  // hoisted E B-frags for the 32-m tile
  half8 bq[2][2];
#pragma unroll
  for (int t = 0; t < 2; ++t) {
    const f16* bp = Qb + ((size_t)(m0 + 16 * t + lr)) * 64 + 8 * lg;
    bq[t][0] = *(const half8*)(bp);
    bq[t][1] = *(const half8*)(bp + 32);
  }

  floatx4 o[4][2];
#pragma unroll
  for (int cs = 0; cs < 4; ++cs)
#pragma unroll
    for (int t = 0; t < 2; ++t) o[cs][t] = (floatx4){0.f, 0.f, 0.f, 0.f};

  // pipeline state (all depth-2, named)
  half8 a0A, a0B, a1A, a1B;
  half4 u0[4], u1[4];
  floatx4 d0A, d0B, d1A, d1B;

  // prologue: steps 0,1 loaded; E(0) issued
  LOADA(w * 16, a0A, a0B); LOADU(w, u0);
  LOADA((w + 8) * 16, a1A, a1B); LOADU(w + 8, u1);
  E_STEP(a0A, a0B, d0A, d0B);
  int sl = w + 16;
#pragma unroll 1
  for (int k = 0; k < 15; ++k) {
    // i odd: SM(i-1) from slot0; load (i+1)->slot0; E(i) from slot1
    SMPV(d0A, d0B, u0);
    LOADA(sl * 16, a0A, a0B); LOADU(sl, u0); sl += 8;
    E_STEP(a1A, a1B, d1A, d1B);
    // i even: SM(i-1) from slot1; load (i+1)->slot1; E(i) from slot0
    SMPV(d1A, d1B, u1);
    LOADA(sl * 16, a1A, a1B); LOADU(sl, u1); sl += 8;
    E_STEP(a0A, a0B, d0A, d0B);
  }
  // i = 31: SM(30); E(31); drain SM(31)
  SMPV(d0A, d0B, u0);
  E_STEP(a1A, a1B, d1A, d1B);
  SMPV(d1A, d1B, u1);

  // ---- 8-wave reduction, fixed order: deterministic, no atomics ----
#pragma unroll 1
  for (int cs = 0; cs < 4; ++cs) {
    __syncthreads();
#pragma unroll
    for (int t = 0; t < 2; ++t)
#pragma unroll
      for (int i = 0; i < 4; ++i)
        red[w][t][4 * lg + i][lr] = o[cs][t][i];
    __syncthreads();
    const int t = tid >> 8;              // 0..1
    const int r = (tid >> 4) & 15;       // 0..15
    const int col = tid & 15;            // 0..15
    float ssum = 0.f;
#pragma unroll
    for (int ww = 0; ww < 8; ++ww) ssum += red[ww][t][r][col];
    Out[((size_t)b * C4C + cs * 16 + r) * NN + m0 + t * 16 + col] = ssum;
  }
}

// ---------------- launch ----------------
// ws layout (~8.45 MB, Zp aliased over U4 region — dead before U4 is written):
//   Qt  f16 [4][4096][64]      2 MiB    @ 0
//   V   f32 [4][64][4096]      4 MiB    @ 2 MiB
//   Z   f32 [4][4096]          64 KiB   @ 6 MiB
//   U4  f16 [4][256][64][16]   2 MiB    @ 6 MiB + 64 KiB
//   Zp  f32 [2][4][4096]       128 KiB  @ 6 MiB + 64 KiB (aliases U4)
extern "C" void kernel_launch(void* const* d_in, const int* in_sizes, int n_in,
                              void* d_out, int out_size, void* d_ws, size_t ws_size,
                              hipStream_t stream)
{
  const float* x   = (const float*)d_in[0];
  const float* Wqk = (const float*)d_in[1];
  const float* Wv  = (const float*)d_in[2];
  const float* bv  = (const float*)d_in[3];
  float* out = (float*)d_out;

  char* ws = (char*)d_ws;
  f16*   Qt = (f16*)(ws);
  float* V  = (float*)(ws + (2u << 20));
  float* Z  = (float*)(ws + (6u << 20));
  f16*   U4 = (f16*)(ws + (6u << 20) + (64u << 10));
  float* Zp = (float*)(ws + (6u << 20) + (64u << 10));  // alias: dead before U4

  qv_kernel<<<dim3(128, 4), 256, 0, stream>>>(x, Wqk, Wv, bv, Qt, V);
  z_kernel<<<dim3(1024), 256, 0, stream>>>(Qt, Zp);
  zr_kernel<<<dim3(64), 256, 0, stream>>>(Zp, Z);
  u_kernel<<<dim3(512), 256, 0, stream>>>(V, Z, U4);
  av_kernel<<<dim3(512), 512, 0, stream>>>(Qt, U4, out);
}